// Round 12
// baseline (9320.910 us; speedup 1.0000x reference)
//
#include <hip/hip_runtime.h>
#include <cmath>

// ESN forward scan on MI355X — round 15: K-split waves (transposed
// intra-block decomposition). Exchange protocol byte-identical to round 12
// (session best 8.09 ms, re-verified 8.12 in r14).
//
// Rationale: the post-last-arrival serial tail in r12 is ~0.5 us:
// unpack->LDS -> barrier -> ds_read h -> 128 fdot2 in 4 depth-32 chains ->
// wave_sum(7 ops incl 2 bpermute) -> tanh -> publish. The LDS h-broadcast
// exists only because waves split by ROWS (each needs all columns).
//
// K-split: wave w owns column chunk [w*1024,(w+1)*1024):
//   * polls ONLY its chunk (same 4 dwordx4/lane, now 64B contiguous);
//   * h stays in REGISTERS (no h LDS, no h barrier);
//   * computes partials for ALL 16 block rows over its 1024 cols:
//     same 128 fdot2/lane, but 16 independent depth-8 chains (4x ILP);
//   * 4 DPP row_ror adds per row -> group sums; lanes {0,16,32,48} write
//     a [16 col-groups][16 rows] fp32 tile to LDS (parity dbuf, 2 KB);
//   * ONE barrier; wave0 lanes 0-15 sum 16 floats, tanh+leak, then all 64
//     lanes of wave0 publish 16 replicas x 16 rows with ONE wave-wide
//     dwordx4 store instruction (lane l -> replica l>>2, rows (l&3)*4..+3).
// Post-arrival tail ~0.25 us; partials overlap arrival jitter (pre-barrier).
//
// Safety: comb parity-dbuf -> writer at t+2 is gated by poll t+2 (-> wave0
// published t+1 -> wave0 long done reading comb[t&1]). No other cross-step
// LDS reuse. Exchange/tags/DLL unchanged.
//
// Predicted: dur 7.2-7.7 ms; FETCH ~600 MB / WRITE ~2.19 GB UNCHANGED
// (control: only intra-block dataflow changed); VALUBusy 20-24%. If
// >=8.0 ms: null -> revert to r12 and declare <<ROOFLINE>> (latency floor).

#define T_STEPS  4096
#define R_SIZE   4096
#define I_SIZE   3
#define OUT_COLS (R_SIZE + I_SIZE)   // 4099
#define NB       256                 // blocks == CUs; all co-resident
#define BT       256                 // threads per block (4 waves)
#define RPB      16                  // rows per block
#define NREP     16                  // exchange replicas (fan-in spreading)
#define LEAK     0.1f

typedef _Float16 h2 __attribute__((ext_vector_type(2)));
typedef unsigned u32x4 __attribute__((ext_vector_type(4)));

__device__ __forceinline__ float fdot2f(h2 a, h2 b, float c) {
#if __has_builtin(__builtin_amdgcn_fdot2)
    return __builtin_amdgcn_fdot2(a, b, c, false);
#else
    return c + (float)a[0] * (float)b[0] + (float)a[1] * (float)b[1];
#endif
}

// tanh via 2^x: tanh(|s|) = (1-e)/(1+e), e = exp2(-2*log2e*|s|). Error
// ~1e-6, far below the 3.9e-3 fp16 exchange quantization already accepted.
__device__ __forceinline__ float fast_tanhf(float s) {
    float av = __builtin_fabsf(s);
    float e  = __builtin_amdgcn_exp2f(-2.8853900817779268f * av);
    float r  = (1.0f - e) * __builtin_amdgcn_rcpf(1.0f + e);
    return __builtin_copysignf(r, s);
}

// 16 tagged words in flight with L1/L2 bypass, one waitcnt. Per-lane the 4
// loads are 64B contiguous (this wave's chunk slice).
__device__ __forceinline__ void poll16(const unsigned* p0, const unsigned* p1,
                                       const unsigned* p2, const unsigned* p3,
                                       u32x4& a0, u32x4& a1, u32x4& a2, u32x4& a3) {
    asm volatile(
        "global_load_dwordx4 %0, %4, off sc0 sc1\n\t"
        "global_load_dwordx4 %1, %5, off sc0 sc1\n\t"
        "global_load_dwordx4 %2, %6, off sc0 sc1\n\t"
        "global_load_dwordx4 %3, %7, off sc0 sc1\n\t"
        "s_waitcnt vmcnt(0)"
        : "=&v"(a0), "=&v"(a1), "=&v"(a2), "=&v"(a3)
        : "v"(p0), "v"(p1), "v"(p2), "v"(p3)
        : "memory");
}

// v_perm-paired tag check: pack two hi-half tags per dword, xor vs splat.
__device__ __forceinline__ unsigned tagbad4(const u32x4& a, unsigned tg2) {
    unsigned t01 = __builtin_amdgcn_perm(a[1], a[0], 0x07060302u) ^ tg2;
    unsigned t23 = __builtin_amdgcn_perm(a[3], a[2], 0x07060302u) ^ tg2;
    return t01 | t23;
}
__device__ __forceinline__ int check16(const u32x4& a0, const u32x4& a1,
                                       const u32x4& a2, const u32x4& a3,
                                       unsigned tg2) {
    unsigned bad = tagbad4(a0, tg2) | tagbad4(a1, tg2) |
                   tagbad4(a2, tg2) | tagbad4(a3, tg2);
    return bad == 0u;
}

template<int CTRL>
__device__ __forceinline__ float dpp_ror_add(float a) {
    int r = __builtin_amdgcn_update_dpp(0, __builtin_bit_cast(int, a),
                                        CTRL, 0xF, 0xF, false);
    return a + __builtin_bit_cast(float, r);
}
// reduce within each 16-lane group (all lanes end with the group sum)
__device__ __forceinline__ float group16_sum(float a) {
    a = dpp_ror_add<0x128>(a);   // row_ror:8
    a = dpp_ror_add<0x124>(a);   // row_ror:4
    a = dpp_ror_add<0x122>(a);   // row_ror:2
    a = dpp_ror_add<0x121>(a);   // row_ror:1
    return a;
}

__device__ __forceinline__ h2 lo_pair(unsigned wa, unsigned wb) {
    // pack {lo16(wa), lo16(wb)} -> h2
    return __builtin_bit_cast(h2, __builtin_amdgcn_perm(wb, wa, 0x05040100u));
}

__global__ void __launch_bounds__(BT, 1) esn_kernel(
    const float* __restrict__ Wh,    // [R, R] row-major fp32
    const float* __restrict__ Win,   // [R, 3]
    const float* __restrict__ x,     // [T, 3]
    float* __restrict__ out,         // [T, 4099]
    unsigned* __restrict__ ex0,      // even-step reads: nrep x R dwords
    unsigned* __restrict__ ex1,      // odd-step reads:  nrep x R dwords
    unsigned rep_mask)               // nrep-1 (16/8/1 by ws_size)
{
    __shared__ float comb[2][16][16];        // [parity][col-group][row], 2 KB
    __shared__ float xs[T_STEPS * I_SIZE];   // 48 KB

    const int tid  = threadIdx.x;
    const int bid  = blockIdx.x;
    const int wv   = tid >> 6;
    const int lane = tid & 63;
    const int r0   = bid * RPB;

    // ---- one-time: weights. Wave w holds ALL 16 rows x its 1024-col
    //      chunk; lane l covers cols wv*1024 + l*16 .. +15. 128 VGPRs. ----
    h2 wreg[RPB][8];
    #pragma unroll
    for (int r = 0; r < RPB; ++r) {
        const float* src = Wh + (size_t)(r0 + r) * R_SIZE + wv * 1024 + lane * 16;
        float4 A = *(const float4*)(src + 0);
        float4 B = *(const float4*)(src + 4);
        float4 C = *(const float4*)(src + 8);
        float4 D = *(const float4*)(src + 12);
        wreg[r][0][0] = (_Float16)A.x; wreg[r][0][1] = (_Float16)A.y;
        wreg[r][1][0] = (_Float16)A.z; wreg[r][1][1] = (_Float16)A.w;
        wreg[r][2][0] = (_Float16)B.x; wreg[r][2][1] = (_Float16)B.y;
        wreg[r][3][0] = (_Float16)B.z; wreg[r][3][1] = (_Float16)B.w;
        wreg[r][4][0] = (_Float16)C.x; wreg[r][4][1] = (_Float16)C.y;
        wreg[r][5][0] = (_Float16)C.z; wreg[r][5][1] = (_Float16)C.w;
        wreg[r][6][0] = (_Float16)D.x; wreg[r][6][1] = (_Float16)D.y;
        wreg[r][7][0] = (_Float16)D.z; wreg[r][7][1] = (_Float16)D.w;
    }

    // ---- one-time: stage x into LDS ----
    for (int i = tid; i < T_STEPS * I_SIZE; i += BT) xs[i] = x[i];

    // finisher lanes: wave 0, lanes 0-15 own row r0+lane (Win + leak state)
    float win0 = 0.f, win1 = 0.f, win2 = 0.f;
    if (wv == 0 && lane < RPB) {
        int r = r0 + lane;
        win0 = Win[(size_t)r * I_SIZE + 0];
        win1 = Win[(size_t)r * I_SIZE + 1];
        win2 = Win[(size_t)r * I_SIZE + 2];
    }
    float hown = 0.0f;   // h0 = 0

    // poll pointers: wave wv polls ITS chunk of replica (bid & rep_mask):
    // lane l owns words wv*1024 + l*16 .. +15 (4 consecutive dwordx4).
    const unsigned rep = (unsigned)bid & rep_mask;
    const unsigned* pb[2];
    pb[0] = ex0 + rep * R_SIZE + wv * 1024 + lane * 16;
    pb[1] = ex1 + rep * R_SIZE + wv * 1024 + lane * 16;

    __syncthreads();     // xs visible

    // ---- delay-locked pacing state (per wave, wave-uniform scalars) ----
    unsigned long long tgt = 0;
    unsigned P = 0;

    for (int t = 0; t < T_STEPS; ++t) {
        const int par = t & 1;
        unsigned* __restrict__ exw = par ? ex0 : ex1;   // publish tag t+1

        // ---- u = x*Win: independent of h -> compute before the poll ----
        float u = 0.0f;
        if (wv == 0 && lane < RPB)
            u = xs[t * 3 + 0] * win0 + xs[t * 3 + 1] * win1 +
                xs[t * 3 + 2] * win2;

        // ---- pace: sleep until predicted arrival (bounded) ----
        if (P) {
            for (int i = 0; i < 4096; ++i) {
                if (__builtin_amdgcn_s_memrealtime() >= tgt) break;
                __builtin_amdgcn_s_sleep(2);
            }
        }

        // ---- poll own chunk; straggler-only re-poll ----
        u32x4 a0, a1, a2, a3;
        const unsigned tg2 = (unsigned)t * 0x00010001u;
        const unsigned* pp = pb[par];
        poll16(pp, pp + 4, pp + 8, pp + 12, a0, a1, a2, a3);
        int ok = check16(a0, a1, a2, a3, tg2);
        const int missed = !__all(ok);
        if (missed) {
            do {
                __builtin_amdgcn_s_sleep(1);
                if (!ok) {
                    poll16(pp, pp + 4, pp + 8, pp + 12, a0, a1, a2, a3);
                    ok = check16(a0, a1, a2, a3, tg2);
                }
            } while (!__all(ok));
        }

        // ---- unpack 16 h to registers (no LDS): 8 h2 via v_perm ----
        h2 hh[8];
        hh[0] = lo_pair(a0[0], a0[1]); hh[1] = lo_pair(a0[2], a0[3]);
        hh[2] = lo_pair(a1[0], a1[1]); hh[3] = lo_pair(a1[2], a1[3]);
        hh[4] = lo_pair(a2[0], a2[1]); hh[5] = lo_pair(a2[2], a2[3]);
        hh[6] = lo_pair(a3[0], a3[1]); hh[7] = lo_pair(a3[2], a3[3]);

        // ---- partial dots: ALL 16 rows over this lane's 16 cols.
        //      16 independent depth-8 fdot2 chains (high ILP). ----
        float acc[RPB];
        #pragma unroll
        for (int r = 0; r < RPB; ++r) {
            float s = 0.0f;
            #pragma unroll
            for (int j = 0; j < 8; ++j)
                s = fdot2f(wreg[r][j], hh[j], s);
            acc[r] = group16_sum(s);   // 4 DPP adds: 16-lane group partial
        }

        // ---- combine: lanes {0,16,32,48} write their group's 16 row
        //      partials (col-group c = wv*4 + lane/16) as 4 ds_write_b128.
        if ((lane & 15) == 0) {
            const int c = wv * 4 + (lane >> 4);
            float4* q = (float4*)&comb[par][c][0];
            q[0] = make_float4(acc[0],  acc[1],  acc[2],  acc[3]);
            q[1] = make_float4(acc[4],  acc[5],  acc[6],  acc[7]);
            q[2] = make_float4(acc[8],  acc[9],  acc[10], acc[11]);
            q[3] = make_float4(acc[12], acc[13], acc[14], acc[15]);
        }
        __syncthreads();   // the ONLY per-step barrier

        // ---- wave 0 finishes: lanes 0-15 sum 16 group partials for their
        //      row, tanh+leak, then ALL 64 lanes publish with ONE
        //      wave-wide dwordx4 store (lane l -> replica l>>2,
        //      rows (l&3)*4..+3 gathered via 4 shfl). ----
        if (wv == 0) {
            float hv = 0.0f;
            unsigned word = 0;
            if (lane < RPB) {
                float s = 0.0f;
                #pragma unroll
                for (int c = 0; c < 16; ++c) s += comb[par][c][lane];
                float hn = fast_tanhf(u + s);
                hv = LEAK * hown + (1.0f - LEAK) * hn;
                hown = hv;
                word = ((unsigned)(t + 1) << 16) |
                       (unsigned)__builtin_bit_cast(unsigned short, (_Float16)hv);
            }
            const int rq = (lane & 3) * 4;   // row quartet this lane stores
            unsigned w0 = __shfl(word, rq + 0, 64);
            unsigned w1 = __shfl(word, rq + 1, 64);
            unsigned w2 = __shfl(word, rq + 2, 64);
            unsigned w3 = __shfl(word, rq + 3, 64);
            if ((unsigned)(lane >> 2) <= rep_mask) {
                u32x4 pw = {w0, w1, w2, w3};
                unsigned* dst = exw + (unsigned)(lane >> 2) * R_SIZE + r0 + rq;
                asm volatile("global_store_dwordx4 %0, %1, off sc0 sc1"
                             :: "v"(dst), "v"(pw) : "memory");
            }
            // out[] store after publish — off the critical path
            if (lane < RPB) out[(size_t)t * OUT_COLS + (r0 + lane)] = hv;
        }

        // ---- DLL bookkeeping off the critical path ----
        {
            unsigned long long nowp = __builtin_amdgcn_s_memrealtime();
            P = missed ? (P + 8u > 2048u ? 2048u : P + 8u)
                       : (P >= 2u ? P - 2u : 0u);
            tgt = nowp + P;
        }
    }
}

__global__ void copy_x_kernel(const float* __restrict__ x, float* __restrict__ out) {
    int i = blockIdx.x * blockDim.x + threadIdx.x;
    if (i < T_STEPS * I_SIZE) {
        int t = i / I_SIZE, c = i % I_SIZE;
        out[(size_t)t * OUT_COLS + R_SIZE + c] = x[i];
    }
}

extern "C" void kernel_launch(void* const* d_in, const int* in_sizes, int n_in,
                              void* d_out, int out_size, void* d_ws, size_t ws_size,
                              hipStream_t stream) {
    // setup_inputs order: x [T,3], Win [R,3], Wh [R,R]; all fp32.
    const float* x   = (const float*)d_in[0];
    const float* Win = (const float*)d_in[1];
    const float* Wh  = (const float*)d_in[2];
    float* out = (float*)d_out;

    // ws layout: ex0 (nrep*16 KB) | ex1 (nrep*16 KB). nrep = 16 -> 512 KB;
    // fall back to 8 (256 KB) then 1 if ws is small.
    size_t need16 = (size_t)2 * 16 * R_SIZE * sizeof(unsigned);   // 512 KB
    size_t need8  = (size_t)2 *  8 * R_SIZE * sizeof(unsigned);   // 256 KB
    unsigned nrep = (ws_size >= need16) ? 16u : (ws_size >= need8 ? 8u : 1u);
    unsigned rep_mask = nrep - 1u;
    unsigned* ex0 = (unsigned*)d_ws;
    unsigned* ex1 = ex0 + (size_t)nrep * R_SIZE;

    // zero both: ex0 all-zero == (tag 0, h=0) = ready state for step 0;
    // ex1 all-zero == tag 0 != 1, so step-1 readers wait.
    (void)hipMemsetAsync(d_ws, 0, (size_t)2 * nrep * R_SIZE * sizeof(unsigned),
                         stream);

    copy_x_kernel<<<dim3((T_STEPS * I_SIZE + BT - 1) / BT), dim3(BT), 0, stream>>>(x, out);

    void* args[] = {(void*)&Wh, (void*)&Win, (void*)&x, (void*)&out,
                    (void*)&ex0, (void*)&ex1, (void*)&rep_mask};
    hipError_t e = hipLaunchCooperativeKernel((void*)esn_kernel, dim3(NB), dim3(BT),
                                              args, 0, stream);
    if (e != hipSuccess) {
        // Fallback: plain launch; 256 blocks x 4 waves always co-resident.
        esn_kernel<<<dim3(NB), dim3(BT), 0, stream>>>(Wh, Win, x, out,
                                                      ex0, ex1, rep_mask);
    }
}

// Round 13
// 8272.198 us; speedup vs baseline: 1.1268x; 1.1268x over previous
//
#include <hip/hip_runtime.h>
#include <cmath>

// ESN forward scan on MI355X — round 16 = FINAL (round-12 structure,
// session best: 8.09 ms, re-verified 8.12 ms in r14).
//
// r15 (K-split) post-mortem: 9.32 ms — added ILP but lengthened the
// critical path (block barrier + single-finisher wave funnel vs r12's four
// independent per-wave finishers). WRITE halved (contiguous publish) with
// zero gain -> publish BW was never binding. Last lever family closed.
//
// Session ladder (measured): 16.3 -> 12.1 (8x replicas + straggler
// re-poll) -> 11.8 (packed publish) -> 8.87 (DLL pacing) -> 8.70 (16
// replicas + micro) -> 8.09 (DPP wave-sum). Falsified: flag+fence (37.9),
// atomic publish (10.6), L2-fence polling (37.9), realtime slot-lock
// (infra), K-split (9.3).
//
// Remaining 1.97 us/step = compute ~0.55 + cross-XCD store-visibility
// ~0.4 + MALL sweep/load-return ~0.6 + pacing margin ~0.4. Latency floor:
// VALUBusy 20.6%, HBM 4.5%, MfmaUtil 0, occupancy 12.4% — no saturated
// resource. Converged.

#define T_STEPS  4096
#define R_SIZE   4096
#define I_SIZE   3
#define OUT_COLS (R_SIZE + I_SIZE)   // 4099
#define NB       256                 // blocks == CUs; all co-resident
#define BT       256                 // threads per block (4 waves)
#define RPB      16                  // rows per block
#define RPW      4                   // rows per wave
#define NREP     16                  // exchange replicas (fan-in spreading)
#define LEAK     0.1f

typedef _Float16 h2 __attribute__((ext_vector_type(2)));
typedef _Float16 h8 __attribute__((ext_vector_type(8)));
typedef unsigned u32x2 __attribute__((ext_vector_type(2)));
typedef unsigned u32x4 __attribute__((ext_vector_type(4)));

__device__ __forceinline__ float fdot2f(h2 a, h2 b, float c) {
#if __has_builtin(__builtin_amdgcn_fdot2)
    return __builtin_amdgcn_fdot2(a, b, c, false);
#else
    return c + (float)a[0] * (float)b[0] + (float)a[1] * (float)b[1];
#endif
}

// tanh via 2^x: tanh(|s|) = (1-e)/(1+e), e = exp2(-2*log2e*|s|). Error
// ~1e-6, far below the 3.9e-3 fp16 exchange quantization already accepted.
__device__ __forceinline__ float fast_tanhf(float s) {
    float av = __builtin_fabsf(s);
    float e  = __builtin_amdgcn_exp2f(-2.8853900817779268f * av);
    float r  = (1.0f - e) * __builtin_amdgcn_rcpf(1.0f + e);
    return __builtin_copysignf(r, s);
}

// 16 tagged words in flight with L1/L2 bypass, one waitcnt.
__device__ __forceinline__ void poll16(const unsigned* p0, const unsigned* p1,
                                       const unsigned* p2, const unsigned* p3,
                                       u32x4& a0, u32x4& a1, u32x4& a2, u32x4& a3) {
    asm volatile(
        "global_load_dwordx4 %0, %4, off sc0 sc1\n\t"
        "global_load_dwordx4 %1, %5, off sc0 sc1\n\t"
        "global_load_dwordx4 %2, %6, off sc0 sc1\n\t"
        "global_load_dwordx4 %3, %7, off sc0 sc1\n\t"
        "s_waitcnt vmcnt(0)"
        : "=&v"(a0), "=&v"(a1), "=&v"(a2), "=&v"(a3)
        : "v"(p0), "v"(p1), "v"(p2), "v"(p3)
        : "memory");
}

// v_perm-paired tag check: pack two hi-half tags per dword, xor vs splat.
__device__ __forceinline__ unsigned tagbad4(const u32x4& a, unsigned tg2) {
    unsigned t01 = __builtin_amdgcn_perm(a[1], a[0], 0x07060302u) ^ tg2;
    unsigned t23 = __builtin_amdgcn_perm(a[3], a[2], 0x07060302u) ^ tg2;
    return t01 | t23;
}
__device__ __forceinline__ int check16(const u32x4& a0, const u32x4& a1,
                                       const u32x4& a2, const u32x4& a3,
                                       unsigned tg2) {
    unsigned bad = tagbad4(a0, tg2) | tagbad4(a1, tg2) |
                   tagbad4(a2, tg2) | tagbad4(a3, tg2);
    return bad == 0u;
}

// ---- wave-sum, short-chain version ----
// Stage 1: rotate-reduce within each 16-lane DPP row (4 VALU-speed adds).
// Stage 2: fetch the other 3 group-partials IN PARALLEL (independent ops:
//   ds_swizzle lane^16 + ds_bpermute lane^32 and lane^48) and add.
template<int CTRL>
__device__ __forceinline__ float dpp_ror_add(float a) {
    int r = __builtin_amdgcn_update_dpp(0, __builtin_bit_cast(int, a),
                                        CTRL, 0xF, 0xF, false);
    return a + __builtin_bit_cast(float, r);
}
__device__ __forceinline__ float wave_sum(float a, int idx32, int idx48) {
    a = dpp_ror_add<0x128>(a);   // row_ror:8
    a = dpp_ror_add<0x124>(a);   // row_ror:4
    a = dpp_ror_add<0x122>(a);   // row_ror:2
    a = dpp_ror_add<0x121>(a);   // row_ror:1
    int ai = __builtin_bit_cast(int, a);
    float b = __builtin_bit_cast(float, __builtin_amdgcn_ds_swizzle(ai, 0x401F)); // lane^16
    float c = __builtin_bit_cast(float, __builtin_amdgcn_ds_bpermute(idx32, ai)); // lane^32
    float d = __builtin_bit_cast(float, __builtin_amdgcn_ds_bpermute(idx48, ai)); // lane^48
    return (a + b) + (c + d);
}

__global__ void __launch_bounds__(BT, 1) esn_kernel(
    const float* __restrict__ Wh,    // [R, R] row-major fp32
    const float* __restrict__ Win,   // [R, 3]
    const float* __restrict__ x,     // [T, 3]
    float* __restrict__ out,         // [T, 4099]
    unsigned* __restrict__ ex0,      // even-step reads: nrep x R dwords
    unsigned* __restrict__ ex1,      // odd-step reads:  nrep x R dwords
    unsigned rep_mask)               // nrep-1 (16/8/1 by ws_size)
{
    __shared__ alignas(16) unsigned short hl[R_SIZE];   // 8 KB fp16 bits
    __shared__ float xs[T_STEPS * I_SIZE];              // 48 KB

    const int tid  = threadIdx.x;
    const int bid  = blockIdx.x;
    const int wv   = tid >> 6;
    const int lane = tid & 63;
    const int r0   = bid * RPB;
    const int idx32 = ((lane ^ 32) << 2);   // bpermute byte indices
    const int idx48 = ((lane ^ 48) << 2);

    // ---- one-time: this wave's 4 Wh rows -> fp16 registers (128 VGPRs) ----
    h8 wreg[RPW * 8];
    #pragma unroll
    for (int rr = 0; rr < RPW; ++rr) {
        const float* src = Wh + (size_t)(r0 + wv * RPW + rr) * R_SIZE;
        #pragma unroll
        for (int j = 0; j < 8; ++j) {
            int e = (j * 64 + lane) * 8;
            float4 a = *(const float4*)(src + e);
            float4 b = *(const float4*)(src + e + 4);
            h8 hv;
            hv[0] = (_Float16)a.x; hv[1] = (_Float16)a.y;
            hv[2] = (_Float16)a.z; hv[3] = (_Float16)a.w;
            hv[4] = (_Float16)b.x; hv[5] = (_Float16)b.y;
            hv[6] = (_Float16)b.z; hv[7] = (_Float16)b.w;
            wreg[rr * 8 + j] = hv;
        }
    }

    // ---- one-time: stage x into LDS ----
    for (int i = tid; i < T_STEPS * I_SIZE; i += BT) xs[i] = x[i];

    // publisher lanes (lane<4) cache their row's Win and fp32 leak state
    float win0 = 0.f, win1 = 0.f, win2 = 0.f;
    if (lane < RPW) {
        int r = r0 + wv * RPW + lane;
        win0 = Win[(size_t)r * I_SIZE + 0];
        win1 = Win[(size_t)r * I_SIZE + 1];
        win2 = Win[(size_t)r * I_SIZE + 2];
    }
    float hown = 0.0f;   // h0 = 0

    // poll pointers into THIS block's replica: thread tid owns words
    // {m*1024 + tid*4 .. +3}, m = 0..3
    const unsigned rep  = (unsigned)bid & rep_mask;
    const unsigned nrep = rep_mask + 1u;
    const unsigned* pa[2][4];
    #pragma unroll
    for (int m = 0; m < 4; ++m) {
        pa[0][m] = ex0 + rep * R_SIZE + m * 1024 + tid * 4;
        pa[1][m] = ex1 + rep * R_SIZE + m * 1024 + tid * 4;
    }

    __syncthreads();     // xs visible

    // ---- delay-locked pacing state (per wave, wave-uniform scalars) ----
    unsigned long long tgt = 0;   // next poll time; 0 = no pacing yet
    unsigned P = 0;               // sleep ticks after previous publish

    for (int t = 0; t < T_STEPS; ++t) {
        const int par = t & 1;
        unsigned* __restrict__ exw = par ? ex0 : ex1;   // publish tag t+1

        // ---- u = x*Win: independent of h -> compute before the poll ----
        float u = 0.0f;
        if (lane < RPW)
            u = xs[t * 3 + 0] * win0 + xs[t * 3 + 1] * win1 +
                xs[t * 3 + 2] * win2;

        // ---- pace: sleep until predicted arrival (bounded; tgt in the
        //      past no-ops -> free-run; P=0 -> free-run) ----
        if (P) {
            for (int i = 0; i < 4096; ++i) {
                if (__builtin_amdgcn_s_memrealtime() >= tgt) break;
                __builtin_amdgcn_s_sleep(2);
            }
        }

        // ---- poll: first round reads all 16 words; re-rounds only for
        //      lanes still failing (exec-masked -> no traffic). ----
        u32x4 a0, a1, a2, a3;
        const unsigned tg2 = (unsigned)t * 0x00010001u;   // tag splat
        poll16(pa[par][0], pa[par][1], pa[par][2], pa[par][3], a0, a1, a2, a3);
        int ok = check16(a0, a1, a2, a3, tg2);
        const int missed = !__all(ok);
        if (missed) {
            do {
                __builtin_amdgcn_s_sleep(1);
                if (!ok) {
                    poll16(pa[par][0], pa[par][1], pa[par][2], pa[par][3],
                           a0, a1, a2, a3);
                    ok = check16(a0, a1, a2, a3, tg2);
                }
            } while (!__all(ok));
        }

        // ---- unpack to LDS: v_perm lo-half pairs, one 8-B store per m ----
        {
            u32x4 aa[4] = {a0, a1, a2, a3};
            #pragma unroll
            for (int m = 0; m < 4; ++m) {
                u32x2 w;
                w[0] = __builtin_amdgcn_perm(aa[m][1], aa[m][0], 0x05040100u);
                w[1] = __builtin_amdgcn_perm(aa[m][3], aa[m][2], 0x05040100u);
                *(u32x2*)&hl[m * 1024 + tid * 4] = w;
            }
        }
        __syncthreads();   // hl ready for all waves
        // NOTE: no second barrier. A sibling wave's step-t+1 publish (seen
        // by our next poll) data-depends on its step-t hreg reads, so
        // poll-pass at t+1 proves all siblings finished reading hl.

        // ---- per-lane h chunk into registers ----
        h8 hreg[8];
        const h8* hl8 = (const h8*)hl;
        #pragma unroll
        for (int j = 0; j < 8; ++j) hreg[j] = hl8[j * 64 + lane];

        // ---- 4 rows per wave: register weights, dot2-accumulate ----
        float acc[RPW];
        #pragma unroll
        for (int rr = 0; rr < RPW; ++rr) {
            float a = 0.0f;
            #pragma unroll
            for (int j = 0; j < 8; ++j) {
                h8 w8 = wreg[rr * 8 + j];
                h8 hh = hreg[j];
                a = fdot2f(__builtin_shufflevector(w8, w8, 0, 1),
                           __builtin_shufflevector(hh, hh, 0, 1), a);
                a = fdot2f(__builtin_shufflevector(w8, w8, 2, 3),
                           __builtin_shufflevector(hh, hh, 2, 3), a);
                a = fdot2f(__builtin_shufflevector(w8, w8, 4, 5),
                           __builtin_shufflevector(hh, hh, 4, 5), a);
                a = fdot2f(__builtin_shufflevector(w8, w8, 6, 7),
                           __builtin_shufflevector(hh, hh, 6, 7), a);
            }
            acc[rr] = wave_sum(a, idx32, idx48);
        }

        // ---- epilogue: lanes 0-3 finish their row; lanes 0..nrep-1 publish
        //      all replicas with ONE packed dwordx4 store (lane=replica). ----
        float hv = 0.0f;
        unsigned word = 0;
        if (lane < RPW) {
            float a = (lane == 0) ? acc[0]
                    : (lane == 1) ? acc[1]
                    : (lane == 2) ? acc[2] : acc[3];
            float hn = fast_tanhf(u + a);
            hv = LEAK * hown + (1.0f - LEAK) * hn;
            hown = hv;
            word = ((unsigned)(t + 1) << 16) |
                   (unsigned)__builtin_bit_cast(unsigned short, (_Float16)hv);
        }
        unsigned w0 = __shfl(word, 0, 64);
        unsigned w1 = __shfl(word, 1, 64);
        unsigned w2 = __shfl(word, 2, 64);
        unsigned w3 = __shfl(word, 3, 64);
        if ((unsigned)lane < nrep) {
            u32x4 pw = {w0, w1, w2, w3};
            unsigned* dst = exw + (unsigned)lane * R_SIZE + r0 + wv * RPW;
            asm volatile("global_store_dwordx4 %0, %1, off sc0 sc1"
                         :: "v"(dst), "v"(pw) : "memory");
        }

        // ---- DLL bookkeeping off the critical path (post-publish).
        //      miss -> polled too early, +8 ticks; hit -> shave 2. ----
        {
            unsigned long long nowp = __builtin_amdgcn_s_memrealtime();
            P = missed ? (P + 8u > 2048u ? 2048u : P + 8u)
                       : (P >= 2u ? P - 2u : 0u);
            tgt = nowp + P;
        }

        // out[] store after publish — off the critical path
        if (lane < RPW) {
            out[(size_t)t * OUT_COLS + (r0 + wv * RPW + lane)] = hv;
        }
    }
}

__global__ void copy_x_kernel(const float* __restrict__ x, float* __restrict__ out) {
    int i = blockIdx.x * blockDim.x + threadIdx.x;
    if (i < T_STEPS * I_SIZE) {
        int t = i / I_SIZE, c = i % I_SIZE;
        out[(size_t)t * OUT_COLS + R_SIZE + c] = x[i];
    }
}

extern "C" void kernel_launch(void* const* d_in, const int* in_sizes, int n_in,
                              void* d_out, int out_size, void* d_ws, size_t ws_size,
                              hipStream_t stream) {
    // setup_inputs order: x [T,3], Win [R,3], Wh [R,R]; all fp32.
    const float* x   = (const float*)d_in[0];
    const float* Win = (const float*)d_in[1];
    const float* Wh  = (const float*)d_in[2];
    float* out = (float*)d_out;

    // ws layout: ex0 (nrep*16 KB) | ex1 (nrep*16 KB). nrep = 16 -> 512 KB;
    // fall back to 8 (256 KB) then 1 if ws is small.
    size_t need16 = (size_t)2 * 16 * R_SIZE * sizeof(unsigned);   // 512 KB
    size_t need8  = (size_t)2 *  8 * R_SIZE * sizeof(unsigned);   // 256 KB
    unsigned nrep = (ws_size >= need16) ? 16u : (ws_size >= need8 ? 8u : 1u);
    unsigned rep_mask = nrep - 1u;
    unsigned* ex0 = (unsigned*)d_ws;
    unsigned* ex1 = ex0 + (size_t)nrep * R_SIZE;

    // zero both: ex0 all-zero == (tag 0, h=0) = ready state for step 0;
    // ex1 all-zero == tag 0 != 1, so step-1 readers wait.
    (void)hipMemsetAsync(d_ws, 0, (size_t)2 * nrep * R_SIZE * sizeof(unsigned),
                         stream);

    copy_x_kernel<<<dim3((T_STEPS * I_SIZE + BT - 1) / BT), dim3(BT), 0, stream>>>(x, out);

    void* args[] = {(void*)&Wh, (void*)&Win, (void*)&x, (void*)&out,
                    (void*)&ex0, (void*)&ex1, (void*)&rep_mask};
    hipError_t e = hipLaunchCooperativeKernel((void*)esn_kernel, dim3(NB), dim3(BT),
                                              args, 0, stream);
    if (e != hipSuccess) {
        // Fallback: plain launch; 256 blocks x 4 waves always co-resident.
        esn_kernel<<<dim3(NB), dim3(BT), 0, stream>>>(Wh, Win, x, out,
                                                      ex0, ex1, rep_mask);
    }
}